// Round 1
// baseline (11476.032 us; speedup 1.0000x reference)
//
#include <hip/hip_runtime.h>
#include <math.h>

#define NL 24       // layers
#define NB 64       // batch
#define NC 64       // channels
#define NS 256      // skip channels
#define NK 256      // classes
#define NT 512      // threads per block
#define QROWS 765   // sum of dilations (1+2+...+128)*3 per batch

// One block per batch element. The whole generation trajectory for one batch
// runs inside this block; phases are separated by __syncthreads() only.
__global__ __launch_bounds__(NT)
void wavenet_gen(const int* __restrict__ seed,
                 const float* __restrict__ embed,    // [256][64]
                 const float* __restrict__ conv_k,   // [24][2][64][128]
                 const float* __restrict__ conv_b,   // [24][128]
                 const float* __restrict__ res_w,    // [24][64][64]
                 const float* __restrict__ res_b,    // [24][64]
                 const float* __restrict__ skip_w,   // [24][64][256]
                 const float* __restrict__ skip_b,   // [24][256]
                 const float* __restrict__ out0_w,   // [256][256]
                 const float* __restrict__ out0_b,   // [256]
                 const float* __restrict__ out1_w,   // [256][256]
                 const float* __restrict__ out1_b,   // [256]
                 const int* __restrict__ Tptr,
                 float* __restrict__ out,
                 float* __restrict__ ws)
{
    const int b   = blockIdx.x;
    const int tid = threadIdx.x;
    const int T   = *Tptr;   // 128

    __shared__ float xc[NC];          // current x (residual stream)
    __shared__ float xl[2][NC];       // double-buffered x_last prefetch
    __shared__ float hpart[4 * 128];  // conv partial sums
    __shared__ float gg[NC];          // gated activation
    __shared__ float skipv[NS];       // skip accumulator
    __shared__ float hp2[2 * NK];     // head partials
    __shared__ float h0l[NK];         // relu'd hidden
    __shared__ float logl[NK];        // logits (for argmax)
    __shared__ int   cur_sample;

    float* q = ws + (size_t)b * (QROWS * NC);

    // zero this batch's queue rings (harness poisons ws; must re-zero every call)
    for (int idx = tid; idx < QROWS * NC; idx += NT) q[idx] = 0.f;
    if (tid == 0) cur_sample = seed[b];
    __syncthreads();

    float* out_pred = out + (size_t)b * T;
    float* out_log  = out + (size_t)NB * T + (size_t)b * T * NK;

    for (int t = 0; t < T; ++t) {
        // ---- phase E: embed lookup, skip init, layer-0 x_last prefetch ----
        const int smp = cur_sample;
        if (tid < NC) {
            xc[tid] = embed[smp * NC + tid];
        } else if (tid < NC + NS) {
            skipv[tid - NC] = 0.f;
        } else if (tid < NC + NS + NC) {
            // layer 0: dilation 1 -> row 0 of the ring
            xl[0][tid - (NC + NS)] = q[tid - (NC + NS)];
        }
        __syncthreads();

        // ---- layer loop ----
        for (int i = 0; i < NL; ++i) {
            const int di  = 1 << (i & 7);
            const int row = 255 * (i >> 3) + (di - 1) + (t & (di - 1));
            float* qrow = q + (size_t)row * NC;
            const float* xlb = xl[i & 1];

            // phase A: queue write + conv partials
            {
                const int j  = tid & 127;
                const int cc = tid >> 7;       // 0..3
                const int c0 = cc * 16;
                if (tid < NC) qrow[tid] = xc[tid];   // store layer input
                const float* W0 = conv_k + (size_t)i * (2 * NC * 128) + (size_t)c0 * 128 + j;
                const float* W1 = W0 + NC * 128;
                float acc = 0.f;
                #pragma unroll
                for (int c = 0; c < 16; ++c) {
                    acc = fmaf(xlb[c0 + c], W0[c * 128], acc);
                    acc = fmaf(xc[c0 + c],  W1[c * 128], acc);
                }
                hpart[cc * 128 + j] = acc;
            }
            __syncthreads();

            // phase B: reduce conv partials + gate; prefetch next layer's x_last
            if (tid < NC) {
                const int j2 = tid + 64;
                float hA = hpart[tid] + hpart[128 + tid] + hpart[256 + tid] + hpart[384 + tid]
                         + conv_b[i * 128 + tid];
                float hB = hpart[j2] + hpart[128 + j2] + hpart[256 + j2] + hpart[384 + j2]
                         + conv_b[i * 128 + j2];
                float sg = 1.f / (1.f + expf(-hB));
                gg[tid] = tanhf(hA) * sg;
            } else if (tid < 2 * NC && (i + 1) < NL) {
                const int i2   = i + 1;
                const int d2   = 1 << (i2 & 7);
                const int row2 = 255 * (i2 >> 3) + (d2 - 1) + (t & (d2 - 1));
                xl[(i + 1) & 1][tid - NC] = q[(size_t)row2 * NC + (tid - NC)];
            }
            __syncthreads();

            // phase C: residual update (threads 0..63) + skip accumulate (64..319)
            if (tid < NC) {
                const float* R = res_w + (size_t)i * (NC * NC) + tid;
                float acc = xc[tid] + res_b[i * NC + tid];
                #pragma unroll 8
                for (int j = 0; j < NC; ++j) acc = fmaf(gg[j], R[j * NC], acc);
                xc[tid] = acc;   // only this thread touched xc[tid] this phase
            } else if (tid < NC + NS) {
                const int s = tid - NC;
                const float* Sw = skip_w + (size_t)i * (NC * NS) + s;
                float acc = skipv[s] + skip_b[i * NS + s];
                #pragma unroll 8
                for (int j = 0; j < NC; ++j) acc = fmaf(gg[j], Sw[j * NS], acc);
                skipv[s] = acc;
            }
            __syncthreads();
        }

        // ---- head: h0 = relu(skip @ out0_w + b0) ----
        {
            const int k    = tid & 255;
            const int half = tid >> 8;
            const float* W  = out0_w + (size_t)(half * 128) * NK + k;
            const float* sv = skipv + half * 128;
            float acc = 0.f;
            #pragma unroll 8
            for (int s2 = 0; s2 < 128; ++s2) acc = fmaf(sv[s2], W[s2 * NK], acc);
            hp2[half * NK + k] = acc;
        }
        __syncthreads();
        if (tid < NK) {
            float v = hp2[tid] + hp2[NK + tid] + out0_b[tid];
            h0l[tid] = v > 0.f ? v : 0.f;
        }
        __syncthreads();

        // ---- head: logits = h0 @ out1_w + b1 ----
        {
            const int k    = tid & 255;
            const int half = tid >> 8;
            const float* W  = out1_w + (size_t)(half * 128) * NK + k;
            const float* hv = h0l + half * 128;
            float acc = 0.f;
            #pragma unroll 8
            for (int s2 = 0; s2 < 128; ++s2) acc = fmaf(hv[s2], W[s2 * NK], acc);
            hp2[half * NK + k] = acc;
        }
        __syncthreads();
        if (tid < NK) {
            float lg = hp2[tid] + hp2[NK + tid] + out1_b[tid];
            logl[tid] = lg;
            out_log[(size_t)t * NK + tid] = lg;
        }
        __syncthreads();

        // ---- argmax (first-index tie-break, matching jnp.argmax) + mu-law ----
        if (tid < 64) {
            float bv = logl[tid];
            int   bi = tid;
            #pragma unroll
            for (int r2 = 1; r2 < 4; ++r2) {
                float v = logl[tid + 64 * r2];
                if (v > bv) { bv = v; bi = tid + 64 * r2; }   // strict > keeps first
            }
            #pragma unroll
            for (int off = 32; off > 0; off >>= 1) {
                float ov = __shfl_down(bv, off);
                int   oi = __shfl_down(bi, off);
                if (ov > bv || (ov == bv && oi < bi)) { bv = ov; bi = oi; }
            }
            if (tid == 0) {
                cur_sample = bi;
                float mw = (float)bi * (2.0f / 255.0f) - 1.0f;
                float a  = fabsf(mw);
                float p  = (exp2f(8.0f * a) - 1.0f) * (1.0f / 255.0f); // 256^a - 1 over 255
                out_pred[t] = (mw < 0.f) ? -p : p;
            }
        }
        __syncthreads();
    }
}

extern "C" void kernel_launch(void* const* d_in, const int* in_sizes, int n_in,
                              void* d_out, int out_size, void* d_ws, size_t ws_size,
                              hipStream_t stream) {
    const int*   seed   = (const int*)  d_in[0];
    const float* embed  = (const float*)d_in[1];
    const float* conv_k = (const float*)d_in[2];
    const float* conv_b = (const float*)d_in[3];
    const float* res_w  = (const float*)d_in[4];
    const float* res_b  = (const float*)d_in[5];
    const float* skip_w = (const float*)d_in[6];
    const float* skip_b = (const float*)d_in[7];
    const float* out0_w = (const float*)d_in[8];
    const float* out0_b = (const float*)d_in[9];
    const float* out1_w = (const float*)d_in[10];
    const float* out1_b = (const float*)d_in[11];
    const int*   Tptr   = (const int*)  d_in[12];

    wavenet_gen<<<dim3(NB), dim3(NT), 0, stream>>>(
        seed, embed, conv_k, conv_b, res_w, res_b, skip_w, skip_b,
        out0_w, out0_b, out1_w, out1_b, Tptr,
        (float*)d_out, (float*)d_ws);
}

// Round 2
// 8045.572 us; speedup vs baseline: 1.4264x; 1.4264x over previous
//
#include <hip/hip_runtime.h>
#include <math.h>

#define NL 24       // layers
#define NB 64       // batch
#define NC 64       // channels
#define NS 256      // skip channels
#define NK 256      // classes
#define NT 512      // threads per block
#define QROWS 765   // sum of dilations per batch

// Per-layer weight fragment held in registers by each thread (double-buffered).
// conv: thread (jc=tid&31, cc=tid>>5) owns cols jc*4..+3, rows cc*8..+7 of [128][128]
// res : thread (jr=tid&15, cr=tid>>4) owns cols jr*4..+3, rows cr*2..+1 of [64][64]
// skip: thread (js=tid&63, cs=tid>>6) owns cols js*4..+3, rows cs*8..+7 of [64][256]
struct WBuf {
    float4 a[8];
    float4 r[2];
    float4 s[8];
};

// Barrier that does NOT drain vmcnt (register weight prefetches stay in flight).
// lgkmcnt(0) gives LDS write->read visibility; memory clobbers pin ds ops.
__device__ __forceinline__ void bar_sync() {
    asm volatile("s_waitcnt lgkmcnt(0)" ::: "memory");
    __builtin_amdgcn_s_barrier();
    asm volatile("" ::: "memory");
}

__device__ __forceinline__ void prefetch_w(WBuf& b, int i, int tid,
                                           const float4* __restrict__ convw4,
                                           const float4* __restrict__ resw4,
                                           const float4* __restrict__ skipw4)
{
    const int jc = tid & 31, cc = tid >> 5;
    const float4* cw = convw4 + (size_t)i * 4096 + (size_t)(cc * 8) * 32 + jc;
#pragma unroll
    for (int k = 0; k < 8; ++k) b.a[k] = cw[k * 32];
    const int jr = tid & 15, cr = tid >> 4;
    const float4* rw = resw4 + (size_t)i * 1024 + (size_t)(cr * 2) * 16 + jr;
#pragma unroll
    for (int k = 0; k < 2; ++k) b.r[k] = rw[k * 16];
    const int js = tid & 63, cs = tid >> 6;
    const float4* sw = skipw4 + (size_t)i * 4096 + (size_t)(cs * 8) * 64 + js;
#pragma unroll
    for (int k = 0; k < 8; ++k) b.s[k] = sw[k * 64];
}

__global__ __launch_bounds__(NT)
void wavenet_gen(const int* __restrict__ seed,
                 const float* __restrict__ embed,    // [256][64]
                 const float* __restrict__ conv_k,   // [24][2][64][128]
                 const float* __restrict__ conv_b,   // [24][128]
                 const float* __restrict__ res_w,    // [24][64][64]
                 const float* __restrict__ res_b,    // [24][64]
                 const float* __restrict__ skip_w,   // [24][64][256]
                 const float* __restrict__ skip_b,   // [24][256]
                 const float* __restrict__ out0_w,   // [256][256]
                 const float* __restrict__ out0_b,
                 const float* __restrict__ out1_w,   // [256][256]
                 const float* __restrict__ out1_b,
                 const int* __restrict__ Tptr,
                 float* __restrict__ out,
                 float* __restrict__ ws)
{
    const int b   = blockIdx.x;
    const int tid = threadIdx.x;
    const int T   = *Tptr;   // 128

    __shared__ __align__(16) float part[4096];      // phase partials (reused)
    __shared__ __align__(16) float cbias[NL * 128]; // conv biases
    __shared__ __align__(16) float rbias[NL * 64];
    __shared__ __align__(16) float sbias[NL * 256];
    __shared__ __align__(16) float o0b[NK], o1b[NK];
    __shared__ float xc[NC], xl[2][NC], gg[NC], skipv[NS], hbuf[NK];
    __shared__ int   sh_smp;

    float* q = ws + (size_t)b * (QROWS * NC);

    // ---- one-time init: zero queue rings, stage biases in LDS ----
    {
        float4* q4 = (float4*)q;
        const float4 z = make_float4(0.f, 0.f, 0.f, 0.f);
        for (int idx = tid; idx < QROWS * NC / 4; idx += NT) q4[idx] = z;
        const float4* s4; float4* d4;
        s4 = (const float4*)conv_b; d4 = (float4*)cbias;
        for (int idx = tid; idx < NL * 128 / 4; idx += NT) d4[idx] = s4[idx];
        s4 = (const float4*)res_b; d4 = (float4*)rbias;
        for (int idx = tid; idx < NL * 64 / 4; idx += NT) d4[idx] = s4[idx];
        s4 = (const float4*)skip_b; d4 = (float4*)sbias;
        for (int idx = tid; idx < NL * 256 / 4; idx += NT) d4[idx] = s4[idx];
        s4 = (const float4*)out0_b; d4 = (float4*)o0b;
        for (int idx = tid; idx < NK / 4; idx += NT) d4[idx] = s4[idx];
        s4 = (const float4*)out1_b; d4 = (float4*)o1b;
        for (int idx = tid; idx < NK / 4; idx += NT) d4[idx] = s4[idx];
    }
    if (tid == 0) sh_smp = seed[b];
    if (tid < NC) xl[0][tid] = 0.f;
    if (tid >= 64 && tid < 64 + NS) skipv[tid - 64] = 0.f;
    __syncthreads();
    if (tid < NC) xc[tid] = embed[(size_t)sh_smp * NC + tid];

    const float4* convw4 = (const float4*)conv_k;
    const float4* resw4  = (const float4*)res_w;
    const float4* skipw4 = (const float4*)skip_w;

    WBuf bufA, bufB;
    prefetch_w(bufA, 0, tid, convw4, resw4, skipw4);
    bar_sync();

    float* out_pred = out + (size_t)b * T;
    float* out_log  = out + (size_t)NB * T + (size_t)b * T * NK;

    for (int t = 0; t < T; ++t) {
        auto layer = [&](WBuf& cur, WBuf& nxt, const int i) {
            const int inx = (i + 1 < NL) ? (i + 1) : 0;
            // ---------- phase A: issue prefetches, conv partials ----------
            prefetch_w(nxt, inx, tid, convw4, resw4, skipw4);
            const int d   = 1 << (i & 7);
            const int row = 255 * (i >> 3) + (d - 1) + (t & (d - 1));
            if (tid < NC) q[(size_t)row * NC + tid] = xc[tid]; // queue push
            float rxl = 0.f; int wr_xl = 0;
            if (i + 1 < NL && tid >= 64 && tid < 128) {        // next layer x_last
                const int d2   = 1 << (inx & 7);
                const int row2 = 255 * (inx >> 3) + (d2 - 1) + (t & (d2 - 1));
                rxl = q[(size_t)row2 * NC + (tid - 64)];
                wr_xl = 1;
            }
            {
                const int jc = tid & 31, cc = tid >> 5;
                const float* src = (cc < 8) ? xl[i & 1] : xc;
                const int c0 = (cc & 7) * 8;
                float4 acc = make_float4(0.f, 0.f, 0.f, 0.f);
#pragma unroll
                for (int k = 0; k < 8; ++k) {
                    const float xv = src[c0 + k];
                    acc.x = fmaf(xv, cur.a[k].x, acc.x);
                    acc.y = fmaf(xv, cur.a[k].y, acc.y);
                    acc.z = fmaf(xv, cur.a[k].z, acc.z);
                    acc.w = fmaf(xv, cur.a[k].w, acc.w);
                }
                *(float4*)&part[cc * 128 + jc * 4] = acc;
            }
            bar_sync();
            // ---------- phase B: reduce + gate; stage next x_last ----------
            if (tid < NC) {
                float hA = cbias[i * 128 + tid];
                float hB = cbias[i * 128 + tid + 64];
#pragma unroll
                for (int cc = 0; cc < 16; ++cc) {
                    hA += part[cc * 128 + tid];
                    hB += part[cc * 128 + tid + 64];
                }
                const float sg = 1.f / (1.f + expf(-hB));
                gg[tid] = tanhf(hA) * sg;
            } else if (wr_xl) {
                xl[(i + 1) & 1][tid - 64] = rxl;
            }
            bar_sync();
            // ---------- phase C: res + skip partials ----------
            {
                const int jr = tid & 15, cr = tid >> 4;
                const float g0 = gg[cr * 2], g1 = gg[cr * 2 + 1];
                float4 ar;
                ar.x = fmaf(g0, cur.r[0].x, g1 * cur.r[1].x);
                ar.y = fmaf(g0, cur.r[0].y, g1 * cur.r[1].y);
                ar.z = fmaf(g0, cur.r[0].z, g1 * cur.r[1].z);
                ar.w = fmaf(g0, cur.r[0].w, g1 * cur.r[1].w);
                *(float4*)&part[cr * 64 + jr * 4] = ar;

                const int js = tid & 63, cs = tid >> 6;
                const int c0 = cs * 8;
                float4 as = make_float4(0.f, 0.f, 0.f, 0.f);
#pragma unroll
                for (int k = 0; k < 8; ++k) {
                    const float gv = gg[c0 + k];
                    as.x = fmaf(gv, cur.s[k].x, as.x);
                    as.y = fmaf(gv, cur.s[k].y, as.y);
                    as.z = fmaf(gv, cur.s[k].z, as.z);
                    as.w = fmaf(gv, cur.s[k].w, as.w);
                }
                *(float4*)&part[2048 + cs * 256 + js * 4] = as;
            }
            bar_sync();
            // ---------- phase D: reduce res into xc, skip into skipv ----------
            if (tid < NC) {
                float acc = xc[tid] + rbias[i * 64 + tid];
#pragma unroll
                for (int cr = 0; cr < 32; ++cr) acc += part[cr * 64 + tid];
                xc[tid] = acc;
            } else if (tid < 64 + NS) {
                const int s = tid - 64;
                float acc = skipv[s] + sbias[i * 256 + s];
#pragma unroll
                for (int cs = 0; cs < 8; ++cs) acc += part[2048 + cs * 256 + s];
                skipv[s] = acc;
            }
            bar_sync();
        };

#pragma unroll 1
        for (int ii = 0; ii < NL; ii += 2) {
            layer(bufA, bufB, ii);
            layer(bufB, bufA, ii + 1);
        }

        // ---------- head GEMV 1: h0 = relu(skipv @ out0_w + b0) ----------
        {
            const int jh = tid & 63, ch = tid >> 6;
            const float4* wp = (const float4*)out0_w + (size_t)(ch * 32) * 64 + jh;
            float4 acc = make_float4(0.f, 0.f, 0.f, 0.f);
#pragma unroll
            for (int k = 0; k < 32; ++k) {
                const float xv = skipv[ch * 32 + k];
                acc.x = fmaf(xv, wp[k * 64].x, acc.x);
                acc.y = fmaf(xv, wp[k * 64].y, acc.y);
                acc.z = fmaf(xv, wp[k * 64].z, acc.z);
                acc.w = fmaf(xv, wp[k * 64].w, acc.w);
            }
            *(float4*)&part[ch * 256 + jh * 4] = acc;
        }
        bar_sync();
        if (tid < NK) {
            float v = o0b[tid];
#pragma unroll
            for (int ch = 0; ch < 8; ++ch) v += part[ch * 256 + tid];
            hbuf[tid] = fmaxf(v, 0.f);
        }
        bar_sync();
        // ---------- head GEMV 2: logits = h0 @ out1_w + b1 ----------
        {
            const int jh = tid & 63, ch = tid >> 6;
            const float4* wp = (const float4*)out1_w + (size_t)(ch * 32) * 64 + jh;
            float4 acc = make_float4(0.f, 0.f, 0.f, 0.f);
#pragma unroll
            for (int k = 0; k < 32; ++k) {
                const float xv = hbuf[ch * 32 + k];
                acc.x = fmaf(xv, wp[k * 64].x, acc.x);
                acc.y = fmaf(xv, wp[k * 64].y, acc.y);
                acc.z = fmaf(xv, wp[k * 64].z, acc.z);
                acc.w = fmaf(xv, wp[k * 64].w, acc.w);
            }
            *(float4*)&part[ch * 256 + jh * 4] = acc;
        }
        bar_sync();
        if (tid < NK) {
            float lg = o1b[tid];
#pragma unroll
            for (int ch = 0; ch < 8; ++ch) lg += part[ch * 256 + tid];
            hbuf[tid] = lg;                       // reuse hbuf for logits
            out_log[(size_t)t * NK + tid] = lg;
        }
        bar_sync();
        // ---------- argmax (first-index tie-break) + inverse mu-law ----------
        if (tid < 64) {
            float bv = hbuf[tid];
            int   bi = tid;
#pragma unroll
            for (int r2 = 1; r2 < 4; ++r2) {
                const float v = hbuf[tid + 64 * r2];
                if (v > bv) { bv = v; bi = tid + 64 * r2; }
            }
#pragma unroll
            for (int off = 32; off > 0; off >>= 1) {
                const float ov = __shfl_down(bv, off);
                const int   oi = __shfl_down(bi, off);
                if (ov > bv || (ov == bv && oi < bi)) { bv = ov; bi = oi; }
            }
            if (tid == 0) {
                sh_smp = bi;
                const float mw = (float)bi * (2.0f / 255.0f) - 1.0f;
                const float a  = fabsf(mw);
                const float p  = (exp2f(8.0f * a) - 1.0f) * (1.0f / 255.0f);
                out_pred[t] = (mw < 0.f) ? -p : p;
            }
        }
        bar_sync();
        // ---------- phase E: next-step embed lookup, layer-0 x_last, skip reset ----------
        if (tid < NC) {
            xc[tid] = embed[(size_t)sh_smp * NC + tid];
        } else if (tid < 128) {
            xl[0][tid - 64] = q[tid - 64];   // layer 0: dilation 1 -> ring row 0
        } else if (tid < 128 + NS) {
            skipv[tid - 128] = 0.f;
        }
        bar_sync();
    }
}

extern "C" void kernel_launch(void* const* d_in, const int* in_sizes, int n_in,
                              void* d_out, int out_size, void* d_ws, size_t ws_size,
                              hipStream_t stream) {
    const int*   seed   = (const int*)  d_in[0];
    const float* embed  = (const float*)d_in[1];
    const float* conv_k = (const float*)d_in[2];
    const float* conv_b = (const float*)d_in[3];
    const float* res_w  = (const float*)d_in[4];
    const float* res_b  = (const float*)d_in[5];
    const float* skip_w = (const float*)d_in[6];
    const float* skip_b = (const float*)d_in[7];
    const float* out0_w = (const float*)d_in[8];
    const float* out0_b = (const float*)d_in[9];
    const float* out1_w = (const float*)d_in[10];
    const float* out1_b = (const float*)d_in[11];
    const int*   Tptr   = (const int*)  d_in[12];

    wavenet_gen<<<dim3(NB), dim3(NT), 0, stream>>>(
        seed, embed, conv_k, conv_b, res_w, res_b, skip_w, skip_b,
        out0_w, out0_b, out1_w, out1_b, Tptr,
        (float*)d_out, (float*)d_ws);
}

// Round 3
// 6613.314 us; speedup vs baseline: 1.7353x; 1.2166x over previous
//
#include <hip/hip_runtime.h>
#include <math.h>

#define NBATCH 64
#define NLAY   24
#define TPB    512
#define QROWS  765
#define QFLOATS ((size_t)NBATCH * QROWS * 64)     // 3,133,440 floats of ws for queue rings
#define PACKW_F4 ((size_t)NLAY * 8 * 18 * 64)     // per-lane packed layer weights (float4 units)

// Per-lane register fragment of one layer's weights (18 float4 = 72 floats):
//  v[0..3]  conv col c      = w*8+(l&7), k = (l>>3)*16 + j*4 + m   (k<64: tap0/x_last, k>=64: tap1/x_cur)
//  v[4..7]  conv col c+64, same k
//  v[8..9]  res  col c,      k = (l>>3)*8  + (j-8)*4 + m
//  v[10..13] skip col s0     = w*32+(l&15)*2, k = (l>>4)*16 + (j-10)*4 + m
//  v[14..17] skip col s0+1, same k
struct WB { float4 v[18]; };

__device__ __forceinline__ float hadd4(float4 v) { return (v.x + v.y) + (v.z + v.w); }
__device__ __forceinline__ void fma4(float4& a, float4 x, float4 w) {
    a.x = fmaf(x.x, w.x, a.x); a.y = fmaf(x.y, w.y, a.y);
    a.z = fmaf(x.z, w.z, a.z); a.w = fmaf(x.w, w.w, a.w);
}

// Barrier that does NOT drain vmcnt: register weight prefetches stay in flight.
__device__ __forceinline__ void bar() {
    asm volatile("s_waitcnt lgkmcnt(0)" ::: "memory");
    __builtin_amdgcn_s_barrier();
    asm volatile("" ::: "memory");
}

__device__ __forceinline__ void pf(WB& b, const float4* __restrict__ packW, int i, int w, int l) {
    const float4* p = packW + ((size_t)(i * 8 + w) * 18) * 64 + l;
#pragma unroll
    for (int j = 0; j < 18; ++j) b.v[j] = p[j * 64];
}

// ---------------- repack: swizzle weights into lane-major coalesced layout ----------------
__global__ void repack(const float* __restrict__ conv_k, const float* __restrict__ res_w,
                       const float* __restrict__ skip_w, const float* __restrict__ out0_w,
                       const float* __restrict__ out1_w, float* __restrict__ ws) {
    const int l = threadIdx.x;
    const int bb = blockIdx.x;
    float4* packW = (float4*)(ws + QFLOATS);
    float4* packH = packW + PACKW_F4;
    if (bb < NLAY * 8) {
        const int i = bb >> 3, w = bb & 7;
        float4* dst = packW + (size_t)bb * 18 * 64 + l;
        const int c  = w * 8 + (l & 7);
        const int kb = (l >> 3) * 16;
#pragma unroll
        for (int j = 0; j < 4; ++j) {           // conv col c
            float4 v;
            int k0 = kb + j * 4;
            v.x = conv_k[(((size_t)i * 2 + ((k0+0) >> 6)) * 64 + ((k0+0) & 63)) * 128 + c];
            v.y = conv_k[(((size_t)i * 2 + ((k0+1) >> 6)) * 64 + ((k0+1) & 63)) * 128 + c];
            v.z = conv_k[(((size_t)i * 2 + ((k0+2) >> 6)) * 64 + ((k0+2) & 63)) * 128 + c];
            v.w = conv_k[(((size_t)i * 2 + ((k0+3) >> 6)) * 64 + ((k0+3) & 63)) * 128 + c];
            dst[j * 64] = v;
        }
#pragma unroll
        for (int j = 0; j < 4; ++j) {           // conv col c+64
            float4 v;
            int k0 = kb + j * 4; int c2 = c + 64;
            v.x = conv_k[(((size_t)i * 2 + ((k0+0) >> 6)) * 64 + ((k0+0) & 63)) * 128 + c2];
            v.y = conv_k[(((size_t)i * 2 + ((k0+1) >> 6)) * 64 + ((k0+1) & 63)) * 128 + c2];
            v.z = conv_k[(((size_t)i * 2 + ((k0+2) >> 6)) * 64 + ((k0+2) & 63)) * 128 + c2];
            v.w = conv_k[(((size_t)i * 2 + ((k0+3) >> 6)) * 64 + ((k0+3) & 63)) * 128 + c2];
            dst[(4 + j) * 64] = v;
        }
        const int kr = (l >> 3) * 8;
#pragma unroll
        for (int j = 0; j < 2; ++j) {           // res col c
            float4 v; int k0 = kr + j * 4;
            v.x = res_w[((size_t)i * 64 + k0 + 0) * 64 + c];
            v.y = res_w[((size_t)i * 64 + k0 + 1) * 64 + c];
            v.z = res_w[((size_t)i * 64 + k0 + 2) * 64 + c];
            v.w = res_w[((size_t)i * 64 + k0 + 3) * 64 + c];
            dst[(8 + j) * 64] = v;
        }
        const int s0 = w * 32 + (l & 15) * 2;
        const int ks = (l >> 4) * 16;
#pragma unroll
        for (int j = 0; j < 4; ++j) {           // skip col s0
            float4 v; int k0 = ks + j * 4;
            v.x = skip_w[((size_t)i * 64 + k0 + 0) * 256 + s0];
            v.y = skip_w[((size_t)i * 64 + k0 + 1) * 256 + s0];
            v.z = skip_w[((size_t)i * 64 + k0 + 2) * 256 + s0];
            v.w = skip_w[((size_t)i * 64 + k0 + 3) * 256 + s0];
            dst[(10 + j) * 64] = v;
        }
#pragma unroll
        for (int j = 0; j < 4; ++j) {           // skip col s0+1
            float4 v; int k0 = ks + j * 4; int s1 = s0 + 1;
            v.x = skip_w[((size_t)i * 64 + k0 + 0) * 256 + s1];
            v.y = skip_w[((size_t)i * 64 + k0 + 1) * 256 + s1];
            v.z = skip_w[((size_t)i * 64 + k0 + 2) * 256 + s1];
            v.w = skip_w[((size_t)i * 64 + k0 + 3) * 256 + s1];
            dst[(14 + j) * 64] = v;
        }
    } else {
        const int hb = bb - NLAY * 8;           // 0..15: [which 0/1][wave]
        const int which = hb >> 3, w = hb & 7;
        const float* W = which ? out1_w : out0_w;
        float4* dst = packH + (size_t)hb * 32 * 64 + l;
        const int c  = w * 32 + (l & 31);
        const int kb = (l >> 5) * 128;
        for (int j = 0; j < 32; ++j) {
            float4 v; int k0 = kb + j * 4;
            v.x = W[(size_t)(k0 + 0) * 256 + c];
            v.y = W[(size_t)(k0 + 1) * 256 + c];
            v.z = W[(size_t)(k0 + 2) * 256 + c];
            v.w = W[(size_t)(k0 + 3) * 256 + c];
            dst[j * 64] = v;
        }
    }
}

// ---------------- main generator: one block per batch, 8 waves ----------------
__global__ __launch_bounds__(TPB, 2)
void wavenet_gen(const int* __restrict__ seed,
                 const float* __restrict__ embed,
                 const float* __restrict__ conv_b,
                 const float* __restrict__ res_b,
                 const float* __restrict__ skip_b,
                 const float* __restrict__ out0_b,
                 const float* __restrict__ out1_b,
                 const int* __restrict__ Tptr,
                 float* __restrict__ out,
                 float* __restrict__ ws)
{
    const int b   = blockIdx.x;
    const int tid = threadIdx.x;
    const int w   = tid >> 6;
    const int l   = tid & 63;
    const int T   = *Tptr;

    __shared__ __align__(16) float x2[128];          // [0..63] x_last staging, [64..127] x_cur
    __shared__ __align__(16) float gg[64];
    __shared__ __align__(16) float sk_lds[256];
    __shared__ __align__(16) float h0_lds[256];
    __shared__ __align__(16) float ebt[256 * 64];    // embed table
    __shared__ __align__(16) float cb[NLAY * 128];
    __shared__ __align__(16) float rb[NLAY * 64];
    __shared__ __align__(16) float sb[NLAY * 256];
    __shared__ __align__(16) float o0b[256], o1b[256];
    __shared__ float wmaxv[8];
    __shared__ int   wmaxi[8];

    float* q = ws + (size_t)b * (QROWS * 64);
    const float4* packW = (const float4*)(ws + QFLOATS);
    const float4* packH = packW + PACKW_F4;

    // ---- init: zero queue rings; stage embed table + biases into LDS ----
    {
        float4* q4 = (float4*)q;
        const float4 z = make_float4(0.f, 0.f, 0.f, 0.f);
        for (int idx = tid; idx < QROWS * 64 / 4; idx += TPB) q4[idx] = z;
        const float4* s4; float4* d4;
        s4 = (const float4*)embed;  d4 = (float4*)ebt;
        for (int idx = tid; idx < 256 * 64 / 4; idx += TPB) d4[idx] = s4[idx];
        s4 = (const float4*)conv_b; d4 = (float4*)cb;
        for (int idx = tid; idx < NLAY * 128 / 4; idx += TPB) d4[idx] = s4[idx];
        s4 = (const float4*)res_b;  d4 = (float4*)rb;
        for (int idx = tid; idx < NLAY * 64 / 4; idx += TPB) d4[idx] = s4[idx];
        s4 = (const float4*)skip_b; d4 = (float4*)sb;
        for (int idx = tid; idx < NLAY * 256 / 4; idx += TPB) d4[idx] = s4[idx];
        s4 = (const float4*)out0_b; d4 = (float4*)o0b;
        for (int idx = tid; idx < 64; idx += TPB) d4[idx] = s4[idx];
        s4 = (const float4*)out1_b; d4 = (float4*)o1b;
        for (int idx = tid; idx < 64; idx += TPB) d4[idx] = s4[idx];
    }
    __syncthreads();
    if (tid < 64) {
        x2[tid] = 0.f;                                   // x_last(layer0, t=0) = 0
        const int smp = seed[b];
        x2[64 + tid] = ebt[smp * 64 + tid];              // x_cur = embed[seed]
    }
    __syncthreads();

    WB A, B;
    pf(A, packW, 0, w, l);

    float* out_pred = out + (size_t)b * T;
    float* out_log  = out + (size_t)NBATCH * T + (size_t)b * T * 256;

    const int c   = w * 8 + (l & 7);    // conv/res column
    const int kb  = (l >> 3) * 16;      // conv K-chunk
    const int kr  = (l >> 3) * 8;       // res K-chunk
    const int ks  = (l >> 4) * 16;      // skip K-chunk
    const int s0  = w * 32 + (l & 15) * 2; // skip cols s0, s0+1
    const int c2  = w * 32 + (l & 31);  // head column
    const int kb2 = (l >> 5) * 128;     // head K-half

    for (int t = 0; t < T; ++t) {
        float skv0 = 0.f, skv1 = 0.f;

        auto layer = [&](WB& cur, WB& nxt, const int i) {
            const int inx = (i + 1 < NLAY) ? (i + 1) : 0;
            // ---------------- phase alpha ----------------
            // x_last prefetch for next layer (issue FIRST so later vmcnt waits keep pf in flight)
            float xlnext = 0.f;
            if (w == 7) {
                const int d2 = 1 << (inx & 7);
                const int row2 = 255 * (inx >> 3) + (d2 - 1) + (t & (d2 - 1)); // inx==0 -> row 0
                xlnext = q[(size_t)row2 * 64 + l];
            }
            pf(nxt, packW, inx, w, l);
            if (w == 6) {                                 // queue push of this layer's input
                const int d = 1 << (i & 7);
                const int row = 255 * (i >> 3) + (d - 1) + (t & (d - 1));
                q[(size_t)row * 64 + l] = x2[64 + l];
            }
            // conv partials (own K-chunk, cols c and c+64)
            float4 xk0 = *(const float4*)&x2[kb];
            float4 xk1 = *(const float4*)&x2[kb + 4];
            float4 xk2 = *(const float4*)&x2[kb + 8];
            float4 xk3 = *(const float4*)&x2[kb + 12];
            float4 aA = make_float4(0.f, 0.f, 0.f, 0.f);
            float4 aB = make_float4(0.f, 0.f, 0.f, 0.f);
            fma4(aA, xk0, cur.v[0]); fma4(aA, xk1, cur.v[1]);
            fma4(aA, xk2, cur.v[2]); fma4(aA, xk3, cur.v[3]);
            fma4(aB, xk0, cur.v[4]); fma4(aB, xk1, cur.v[5]);
            fma4(aB, xk2, cur.v[6]); fma4(aB, xk3, cur.v[7]);
            float hA = hadd4(aA), hB = hadd4(aB);
            hA += __shfl_xor(hA, 8);  hB += __shfl_xor(hB, 8);
            hA += __shfl_xor(hA, 16); hB += __shfl_xor(hB, 16);
            hA += __shfl_xor(hA, 32); hB += __shfl_xor(hB, 32);
            hA += cb[i * 128 + c];
            hB += cb[i * 128 + 64 + c];
            const float g = tanhf(hA) * (1.f / (1.f + expf(-hB)));
            if (l < 8) gg[w * 8 + l] = g;
            bar();
            // ---------------- phase beta ----------------
            // res partial
            float4 gr0 = *(const float4*)&gg[kr];
            float4 gr1 = *(const float4*)&gg[kr + 4];
            float4 ra = make_float4(0.f, 0.f, 0.f, 0.f);
            fma4(ra, gr0, cur.v[8]); fma4(ra, gr1, cur.v[9]);
            float racc = hadd4(ra);
            racc += __shfl_xor(racc, 8);
            racc += __shfl_xor(racc, 16);
            racc += __shfl_xor(racc, 32);
            const float xnew = x2[64 + c] + racc + rb[i * 64 + c];
            // skip partial
            float4 gs0 = *(const float4*)&gg[ks];
            float4 gs1 = *(const float4*)&gg[ks + 4];
            float4 gs2 = *(const float4*)&gg[ks + 8];
            float4 gs3 = *(const float4*)&gg[ks + 12];
            float4 sa0 = make_float4(0.f, 0.f, 0.f, 0.f);
            float4 sa1 = make_float4(0.f, 0.f, 0.f, 0.f);
            fma4(sa0, gs0, cur.v[10]); fma4(sa0, gs1, cur.v[11]);
            fma4(sa0, gs2, cur.v[12]); fma4(sa0, gs3, cur.v[13]);
            fma4(sa1, gs0, cur.v[14]); fma4(sa1, gs1, cur.v[15]);
            fma4(sa1, gs2, cur.v[16]); fma4(sa1, gs3, cur.v[17]);
            float ss0 = hadd4(sa0), ss1 = hadd4(sa1);
            ss0 += __shfl_xor(ss0, 16); ss1 += __shfl_xor(ss1, 16);
            ss0 += __shfl_xor(ss0, 32); ss1 += __shfl_xor(ss1, 32);
            skv0 += ss0 + sb[i * 256 + s0];
            skv1 += ss1 + sb[i * 256 + s0 + 1];
            if (l < 8) x2[64 + w * 8 + l] = xnew;   // residual out -> x_cur
            if (w == 7) x2[l] = xlnext;             // next layer's x_last
            bar();
        };

#pragma unroll 1
        for (int ii = 0; ii < NLAY; ii += 2) {
            layer(A, B, ii);
            layer(B, A, ii + 1);
        }

        // ---------------- head ----------------
        if (l < 16) { sk_lds[s0] = skv0; sk_lds[s0 + 1] = skv1; }
        bar();
        // GEMV1: h0 = relu(skip @ out0_w + b0)
        {
            const float4* hp = packH + ((size_t)w * 32) * 64 + l;
            float4 ha = make_float4(0.f, 0.f, 0.f, 0.f);
#pragma unroll 8
            for (int cc = 0; cc < 32; ++cc) {
                float4 wv = hp[cc * 64];
                float4 sv = *(const float4*)&sk_lds[kb2 + cc * 4];
                fma4(ha, sv, wv);
            }
            float hs = hadd4(ha);
            hs += __shfl_xor(hs, 32);
            const float h0 = fmaxf(hs + o0b[c2], 0.f);
            if (l < 32) h0_lds[c2] = h0;
        }
        bar();
        // GEMV2: logits = h0 @ out1_w + b1
        float logit;
        {
            const float4* hp = packH + ((size_t)(8 + w) * 32) * 64 + l;
            float4 la = make_float4(0.f, 0.f, 0.f, 0.f);
#pragma unroll 8
            for (int cc = 0; cc < 32; ++cc) {
                float4 wv = hp[cc * 64];
                float4 hv = *(const float4*)&h0_lds[kb2 + cc * 4];
                fma4(la, hv, wv);
            }
            float ls = hadd4(la);
            ls += __shfl_xor(ls, 32);
            logit = ls + o1b[c2];
            if (l < 32) out_log[(size_t)t * 256 + c2] = logit;
        }
        // wave-local argmax over its 32 columns (values replicated across half-waves)
        {
            float bv = logit; int bi = c2;
#pragma unroll
            for (int off = 1; off <= 16; off <<= 1) {
                const float ov = __shfl_xor(bv, off);
                const int   oi = __shfl_xor(bi, off);
                if (ov > bv || (ov == bv && oi < bi)) { bv = ov; bi = oi; }
            }
            if (l == 0) { wmaxv[w] = bv; wmaxi[w] = bi; }
        }
        bar();
        // final: cross-wave argmax, embed lookup, mu-law output
        {
            float fv = wmaxv[0]; int fi = wmaxi[0];
#pragma unroll
            for (int ww = 1; ww < 8; ++ww) {
                const float vv = wmaxv[ww]; const int vi = wmaxi[ww];
                if (vv > fv || (vv == fv && vi < fi)) { fv = vv; fi = vi; }
            }
            if (tid < 64) x2[64 + tid] = ebt[fi * 64 + tid];
            if (tid == 0) {
                const float mw = (float)fi * (2.0f / 255.0f) - 1.0f;
                const float a  = fabsf(mw);
                const float p  = (exp2f(8.0f * a) - 1.0f) * (1.0f / 255.0f);
                out_pred[t] = (mw < 0.f) ? -p : p;
            }
        }
        bar();
    }
}

extern "C" void kernel_launch(void* const* d_in, const int* in_sizes, int n_in,
                              void* d_out, int out_size, void* d_ws, size_t ws_size,
                              hipStream_t stream) {
    const int*   seed   = (const int*)  d_in[0];
    const float* embed  = (const float*)d_in[1];
    const float* conv_k = (const float*)d_in[2];
    const float* conv_b = (const float*)d_in[3];
    const float* res_w  = (const float*)d_in[4];
    const float* res_b  = (const float*)d_in[5];
    const float* skip_w = (const float*)d_in[6];
    const float* skip_b = (const float*)d_in[7];
    const float* out0_w = (const float*)d_in[8];
    const float* out0_b = (const float*)d_in[9];
    const float* out1_w = (const float*)d_in[10];
    const float* out1_b = (const float*)d_in[11];
    const int*   Tptr   = (const int*)  d_in[12];

    repack<<<dim3(NLAY * 8 + 16), dim3(64), 0, stream>>>(
        conv_k, res_w, skip_w, out0_w, out1_w, (float*)d_ws);

    wavenet_gen<<<dim3(NBATCH), dim3(TPB), 0, stream>>>(
        seed, embed, conv_b, res_b, skip_b, out0_b, out1_b, Tptr,
        (float*)d_out, (float*)d_ws);
}